// Round 13
// baseline (137.214 us; speedup 1.0000x reference)
//
#include <hip/hip_runtime.h>
#include <hip/hip_cooperative_groups.h>
#include <math.h>

namespace cg = cooperative_groups;

#define BB 4096
#define DD 1024
#define KK 5
#define PP 1323
#define PTS 7          // points per ptile; 1323 = 189 * 7
#define NPT 189        // p-tiles
#define NBT 16         // b-tiles of 256
#define GRID 512
#define BLK  256

// (2*pi)^(-3/2)
#define INV_2PI_POW15 0.06349363593424097f

// ---- head config ----
#define GR   16        // rows per head block (blocks 0..255)
#define RST  13        // s_red inner stride (12 + 1)
#define CSTR 49        // s_c inner stride
#define NG   13        // param groups of 4
#define WPKN 49152     // packed weight elements

typedef short  bf16x8 __attribute__((ext_vector_type(8)));
typedef float  f32x4  __attribute__((ext_vector_type(4)));

__device__ __forceinline__ short f2bf(float f) {
    union { float f; unsigned u; } x; x.f = f;
    const unsigned r = x.u + 0x7fffu + ((x.u >> 16) & 1u);  // RNE
    return (short)(r >> 16);
}
__device__ __forceinline__ float softplus_f(float x) {
    return (x > 20.f) ? x : log1pf(expf(x));
}

__device__ __forceinline__ int wpk_index(int k, int j) {
    // Wpk[chunk][nt][lane][8]: k = chunk*32 + (lane>>4)*8 + ee, j = nt*16 + (lane&15)
    const int chunk = k >> 5;
    const int kin   = k & 31;
    const int lane  = ((kin >> 3) << 4) | (j & 15);
    const int nt    = j >> 4;
    const int ee    = k & 7;
    return ((chunk * 3 + nt) * 64 + lane) * 8 + ee;
}

// ---------------- device helpers shared by both paths ----------------------

__device__ __forceinline__ void pack_one(int e,
    const float* __restrict__ Wmix, const float* __restrict__ Wmean,
    const float* __restrict__ Wscale, short* __restrict__ Wpk)
{
    int k, j; float v;
    if (e < 5120) {                       // Wmix: [1024][5]
        k = e / 5;  j = e - k * 5;
        v = Wmix[e];
    } else if (e < 17408) {               // Wmean: [1024][12]
        const int idx = e - 5120;
        k = idx / 12; j = 5 + (idx - k * 12);
        v = Wmean[idx];
    } else if (e < 48128) {               // Wscale: [1024][30]
        const int idx = e - 17408;
        k = idx / 30; j = 17 + (idx - k * 30);
        v = Wscale[idx];
    } else {                              // zero-fill j = 47
        k = e - 48128; j = 47; v = 0.f;
    }
    Wpk[wpk_index(k, j)] = f2bf(v);
}

// head block body: block index hb in [0, 256), 256 threads
__device__ __forceinline__ void head_body(int hb, int t,
    const float* __restrict__ rep, const short* __restrict__ Wpk,
    const float* __restrict__ bmix, const float* __restrict__ bmean,
    const float* __restrict__ bscale,
    float* __restrict__ Lout, float* __restrict__ par4,
    float (*s_red)[64][RST], float (*s_c)[CSTR], float (*s_L)[KK][6])
{
    const int w  = t >> 6;          // wave 0..3
    const int l  = t & 63;
    const int lm = l & 15;
    const int lk = (l >> 4) * 8;
    const int b0 = hb * GR;

    f32x4 acc[3] = {f32x4{0,0,0,0}, f32x4{0,0,0,0}, f32x4{0,0,0,0}};

#pragma unroll
    for (int kt = 0; kt < 8; ++kt) {
        const int chunk = w * 8 + kt;        // global 32-k chunk 0..31
        const int kof   = chunk * 32 + lk;

        const float* arow = rep + (size_t)(b0 + lm) * DD + kof;
        const f32x4 a0 = *(const f32x4*)(arow);
        const f32x4 a1 = *(const f32x4*)(arow + 4);

        bf16x8 ah;
#pragma unroll
        for (int u = 0; u < 4; ++u) {
            ah[u]     = f2bf(a0[u]);
            ah[u + 4] = f2bf(a1[u]);
        }

#pragma unroll
        for (int nt = 0; nt < 3; ++nt) {
            const bf16x8 bh = *(const bf16x8*)(Wpk + (((size_t)chunk * 3 + nt) * 64 + l) * 8);
            acc[nt] = __builtin_amdgcn_mfma_f32_16x16x32_bf16(ah, bh, acc[nt], 0, 0, 0);
        }
    }

#pragma unroll
    for (int nt = 0; nt < 3; ++nt)
#pragma unroll
        for (int r = 0; r < 4; ++r)
            s_red[w][l][nt * 4 + r] = acc[nt][r];
    __syncthreads();

    // cooperative sum into s_c[b_loc][j]; C layout [m89]
    for (int e = t; e < GR * 47; e += BLK) {
        const int b_loc = e & 15;
        const int j     = e >> 4;
        const int lane  = ((b_loc >> 2) << 4) | (j & 15);
        const int reg   = ((j >> 4) << 2) | (b_loc & 3);
        s_c[b_loc][j] = s_red[0][lane][reg] + s_red[1][lane][reg]
                      + s_red[2][lane][reg] + s_red[3][lane][reg];
    }
    __syncthreads();

    if (t < GR * KK) {
        const int k     = t >> 4;
        const int b_loc = t & 15;
        const int b     = b0 + b_loc;

        float logits[KK];
#pragma unroll
        for (int kk = 0; kk < KK; ++kk) logits[kk] = s_c[b_loc][kk] + bmix[kk];

        float m[3];
#pragma unroll
        for (int c = 0; c < 3; ++c)
            m[c] = (k > 0) ? (s_c[b_loc][5 + (k - 1) * 3 + c] + bmean[(k - 1) * 3 + c]) : 0.f;

        float sc[6];
#pragma unroll
        for (int c = 0; c < 6; ++c)
            sc[c] = s_c[b_loc][17 + k * 6 + c] + bscale[k * 6 + c];

        float mx = logits[0];
#pragma unroll
        for (int kk = 1; kk < KK; ++kk) mx = fmaxf(mx, logits[kk]);
        float den = 0.f;
#pragma unroll
        for (int kk = 0; kk < KK; ++kk) den += expf(logits[kk] - mx);
        const float wgt = expf(logits[k] - mx) / den;

        const float L00 = softplus_f(sc[0]);
        const float L10 = sc[1];
        const float L11 = softplus_f(sc[2]);
        const float L20 = sc[3];
        const float L21 = sc[4];
        const float L22 = softplus_f(sc[5]);

        const float r00 = 1.f / L00;
        const float r11 = 1.f / L11;
        const float r22 = 1.f / L22;
        const float a   = wgt * r00 * r11 * r22 * INV_2PI_POW15;

        s_L[b_loc][k][0] = L00;
        s_L[b_loc][k][1] = L10;
        s_L[b_loc][k][2] = L11;
        s_L[b_loc][k][3] = L20;
        s_L[b_loc][k][4] = L21;
        s_L[b_loc][k][5] = L22;

        float pv[10] = { m[0], m[1], m[2], r00, L10, r11, L20, L21, r22, a };
#pragma unroll
        for (int i = 0; i < 10; ++i) {
            const int q = k * 10 + i;
            par4[(((size_t)(q >> 2)) * BB + b) * 4 + (q & 3)] = pv[i];
        }
    }
    __syncthreads();

    // coalesced Lout write (720 contiguous floats)
    for (int e = t; e < GR * KK * 9; e += BLK) {
        const int b_loc = e / 45;
        const int rem   = e - b_loc * 45;
        const int k     = rem / 9;
        const int e9    = rem - k * 9;
        const int rr    = e9 / 3;
        const int cc    = e9 - rr * 3;
        const float v = (cc > rr) ? 0.f : s_L[b_loc][k][(rr * (rr + 1)) / 2 + cc];
        Lout[(size_t)b0 * 45 + e] = v;
    }
}

// eval tile body: one b-tile (bt), one ptile
__device__ __forceinline__ void eval_tile(int b, int ptile, const float* pr,
    const float* __restrict__ dxyz, float* __restrict__ out)
{
    const int p0 = ptile * PTS;
#pragma unroll
    for (int i = 0; i < PTS; ++i) {
        const int p = p0 + i;
        const size_t idx = (size_t)p * BB + b;
        const float* xv = dxyz + idx * 3;
        const float x0 = __builtin_nontemporal_load(xv);
        const float x1 = __builtin_nontemporal_load(xv + 1);
        const float x2 = __builtin_nontemporal_load(xv + 2);

        float res = 0.f;
#pragma unroll
        for (int k = 0; k < KK; ++k) {
            const float d0 = x0 - pr[k * 10 + 0];
            const float d1 = x1 - pr[k * 10 + 1];
            const float d2 = x2 - pr[k * 10 + 2];
            const float z0 = d0 * pr[k * 10 + 3];
            const float z1 = fmaf(-pr[k * 10 + 4], z0, d1) * pr[k * 10 + 5];
            const float z2 = fmaf(-pr[k * 10 + 7], z1, fmaf(-pr[k * 10 + 6], z0, d2)) * pr[k * 10 + 8];
            const float q  = fmaf(z2, z2, fmaf(z1, z1, z0 * z0));
            res = fmaf(pr[k * 10 + 9], __expf(-0.5f * q), res);
        }
        __builtin_nontemporal_store(res, &out[idx]);
    }
}

// ---------------------------------------------------------------------------
// Cooperative mega-kernel: pack -> sync -> head -> sync -> eval.
// ---------------------------------------------------------------------------
__global__ __launch_bounds__(BLK, 2) void mega_kernel(
    const float* __restrict__ rep,
    const float* __restrict__ dxyz,
    const float* __restrict__ Wmix,
    const float* __restrict__ bmix,
    const float* __restrict__ Wmean,
    const float* __restrict__ bmean,
    const float* __restrict__ Wscale,
    const float* __restrict__ bscale,
    float* __restrict__ out,
    float* __restrict__ Lout,
    float* __restrict__ par4,
    short* __restrict__ Wpk)
{
    __shared__ float s_red[4][64][RST];
    __shared__ float s_c[GR][CSTR];
    __shared__ float s_L[GR][KK][6];

    cg::grid_group grid = cg::this_grid();

    const int t = threadIdx.x;
    const int g = blockIdx.x;

    // phase 0: pack
    {
        const int e = g * BLK + t;
        if (e < WPKN) pack_one(e, Wmix, Wmean, Wscale, Wpk);
    }
    grid.sync();

    // phase 1: head (blocks 0..255)
    if (g < BB / GR)
        head_body(g, t, rep, Wpk, bmix, bmean, bscale, Lout, par4, s_red, s_c, s_L);
    grid.sync();

    // phase 2: eval
    {
        const int bt = g & (NBT - 1);
        const int b  = bt * BLK + t;

        float pr[NG * 4];
#pragma unroll
        for (int gg = 0; gg < NG; ++gg) {
            const f32x4 v = *(const f32x4*)(par4 + ((size_t)gg * BB + b) * 4);
            pr[gg * 4 + 0] = v[0];
            pr[gg * 4 + 1] = v[1];
            pr[gg * 4 + 2] = v[2];
            pr[gg * 4 + 3] = v[3];
        }

        for (int pt = g >> 4; pt < NPT; pt += GRID / NBT)
            eval_tile(b, pt, pr, dxyz, out);
    }
}

// ---------------------------------------------------------------------------
// Fallback path (R10 structure): separate kernels.
// ---------------------------------------------------------------------------
__global__ __launch_bounds__(256) void pack_kernel(
    const float* __restrict__ Wmix, const float* __restrict__ Wmean,
    const float* __restrict__ Wscale, short* __restrict__ Wpk)
{
    const int e = blockIdx.x * 256 + threadIdx.x;
    if (e < WPKN) pack_one(e, Wmix, Wmean, Wscale, Wpk);
}

__global__ __launch_bounds__(256) void head_kernel_fb(
    const float* __restrict__ rep, const short* __restrict__ Wpk,
    const float* __restrict__ bmix, const float* __restrict__ bmean,
    const float* __restrict__ bscale,
    float* __restrict__ Lout, float* __restrict__ par4)
{
    __shared__ float s_red[4][64][RST];
    __shared__ float s_c[GR][CSTR];
    __shared__ float s_L[GR][KK][6];
    head_body(blockIdx.x, threadIdx.x, rep, Wpk, bmix, bmean, bscale,
              Lout, par4, s_red, s_c, s_L);
}

__global__ __launch_bounds__(256) void eval_kernel_fb(
    const float* __restrict__ dxyz, const float* __restrict__ par4,
    float* __restrict__ out)
{
    const int b = blockIdx.x * 256 + threadIdx.x;
    float pr[NG * 4];
#pragma unroll
    for (int gg = 0; gg < NG; ++gg) {
        const f32x4 v = *(const f32x4*)(par4 + ((size_t)gg * BB + b) * 4);
        pr[gg * 4 + 0] = v[0];
        pr[gg * 4 + 1] = v[1];
        pr[gg * 4 + 2] = v[2];
        pr[gg * 4 + 3] = v[3];
    }
    eval_tile(b, blockIdx.y, pr, dxyz, out);
}

extern "C" void kernel_launch(void* const* d_in, const int* in_sizes, int n_in,
                              void* d_out, int out_size, void* d_ws, size_t ws_size,
                              hipStream_t stream) {
    const float* rep    = (const float*)d_in[0];
    const float* dxyz   = (const float*)d_in[1];
    const float* Wmix   = (const float*)d_in[2];
    const float* bmix   = (const float*)d_in[3];
    const float* Wmean  = (const float*)d_in[4];
    const float* bmean  = (const float*)d_in[5];
    const float* Wscale = (const float*)d_in[6];
    const float* bscale = (const float*)d_in[7];

    float* out  = (float*)d_out;
    float* Lout = out + (size_t)BB * PP;          // second tuple output

    float* par4 = (float*)d_ws;                   // NG*BB*4 f32 (852 KB)
    short* Wpk  = (short*)(par4 + (size_t)NG * BB * 4);  // 49152 bf16 (98 KB)

    void* args[] = {
        (void*)&rep, (void*)&dxyz, (void*)&Wmix, (void*)&bmix,
        (void*)&Wmean, (void*)&bmean, (void*)&Wscale, (void*)&bscale,
        (void*)&out, (void*)&Lout, (void*)&par4, (void*)&Wpk
    };

    hipError_t err = hipLaunchCooperativeKernel((const void*)mega_kernel,
                                                dim3(GRID), dim3(BLK), args, 0, stream);
    if (err != hipSuccess) {
        // deterministic fallback: proven 3-kernel pipeline
        pack_kernel<<<192, 256, 0, stream>>>(Wmix, Wmean, Wscale, Wpk);
        head_kernel_fb<<<BB / GR, 256, 0, stream>>>(rep, Wpk, bmix, bmean, bscale, Lout, par4);
        eval_kernel_fb<<<dim3(BB / 256, NPT), 256, 0, stream>>>(dxyz, par4, out);
    }
}

// Round 14
// 40.389 us; speedup vs baseline: 3.3973x; 3.3973x over previous
//
#include <hip/hip_runtime.h>
#include <math.h>

#define BB 4096
#define DD 1024
#define KK 5
#define PP 1323
#define PTS 7          // points per ptile; 1323 = 189 * 7
#define NPT 189        // p-tiles

// (2*pi)^(-3/2)
#define INV_2PI_POW15 0.06349363593424097f

// ---- head config (R10-proven) ----
#define GR   16        // rows per head block -> 256 blocks
#define NWV  16        // waves per head block
#define RST  13        // s_red inner stride (12 + 1)
#define CSTR 49        // s_c inner stride
#define NG   13        // param groups of 4
#define WPKN 49152     // packed weight elements

typedef short  bf16x8 __attribute__((ext_vector_type(8)));
typedef float  f32x4  __attribute__((ext_vector_type(4)));

__device__ __forceinline__ short f2bf(float f) {
    union { float f; unsigned u; } x; x.f = f;
    const unsigned r = x.u + 0x7fffu + ((x.u >> 16) & 1u);  // RNE
    return (short)(r >> 16);
}
__device__ __forceinline__ float softplus_f(float x) {
    return (x > 20.f) ? x : log1pf(expf(x));
}

__device__ __forceinline__ int wpk_index(int k, int j) {
    // Wpk[chunk][nt][lane][8]: k = chunk*32 + (lane>>4)*8 + ee, j = nt*16 + (lane&15)
    const int chunk = k >> 5;
    const int kin   = k & 31;
    const int lane  = ((kin >> 3) << 4) | (j & 15);
    const int nt    = j >> 4;
    const int ee    = k & 7;
    return ((chunk * 3 + nt) * 64 + lane) * 8 + ee;
}

// ---------------------------------------------------------------------------
// Kernel 0: pack weights -> bf16 MFMA fragment order, coalesced reads.
// ---------------------------------------------------------------------------
__global__ __launch_bounds__(256) void pack_kernel(
    const float* __restrict__ Wmix,
    const float* __restrict__ Wmean,
    const float* __restrict__ Wscale,
    short* __restrict__ Wpk)
{
    const int e = blockIdx.x * 256 + threadIdx.x;   // 0 .. 49151
    int k, j; float v;
    if (e < 5120) {                       // Wmix: [1024][5]
        k = e / 5;  j = e - k * 5;
        v = Wmix[e];
    } else if (e < 17408) {               // Wmean: [1024][12]
        const int i = e - 5120;
        k = i / 12; j = 5 + (i - k * 12);
        v = Wmean[i];
    } else if (e < 48128) {               // Wscale: [1024][30]
        const int i = e - 17408;
        k = i / 30; j = 17 + (i - k * 30);
        v = Wscale[i];
    } else {                              // zero-fill j = 47
        k = e - 48128; j = 47; v = 0.f;
    }
    Wpk[wpk_index(k, j)] = f2bf(v);
}

// ---------------------------------------------------------------------------
// Kernel 1 (identical to R10): fused head. 256 blocks x 1024 thr (16 waves).
// A direct from global, B from packed Wpk, 16-deep LDS reduce, (b,k) tail,
// coalesced Lout write.
// ---------------------------------------------------------------------------
__global__ __launch_bounds__(1024, 4) void head_fused_kernel(
    const float* __restrict__ rep,
    const short* __restrict__ Wpk,
    const float* __restrict__ bmix,
    const float* __restrict__ bmean,
    const float* __restrict__ bscale,
    float* __restrict__ Lout,
    float* __restrict__ par4)
{
    __shared__ float s_red[NWV][64][RST];   // 53.2 KB
    __shared__ float s_c[GR][CSTR];         // 3.1 KB
    __shared__ float s_L[GR][KK][6];        // 1.9 KB

    const int t  = threadIdx.x;
    const int w  = t >> 6;          // wave 0..15
    const int l  = t & 63;
    const int lm = l & 15;
    const int lk = (l >> 4) * 8;
    const int b0 = blockIdx.x * GR;

    f32x4 acc[3] = {f32x4{0,0,0,0}, f32x4{0,0,0,0}, f32x4{0,0,0,0}};

#pragma unroll
    for (int kt = 0; kt < 2; ++kt) {
        const int chunk = w * 2 + kt;        // global 32-k chunk 0..31
        const int kof   = chunk * 32 + lk;

        const float* arow = rep + (size_t)(b0 + lm) * DD + kof;
        const f32x4 a0 = *(const f32x4*)(arow);
        const f32x4 a1 = *(const f32x4*)(arow + 4);

        bf16x8 ah;
#pragma unroll
        for (int u = 0; u < 4; ++u) {
            ah[u]     = f2bf(a0[u]);
            ah[u + 4] = f2bf(a1[u]);
        }

#pragma unroll
        for (int nt = 0; nt < 3; ++nt) {
            const bf16x8 bh = *(const bf16x8*)(Wpk + (((size_t)chunk * 3 + nt) * 64 + l) * 8);
            acc[nt] = __builtin_amdgcn_mfma_f32_16x16x32_bf16(ah, bh, acc[nt], 0, 0, 0);
        }
    }

#pragma unroll
    for (int nt = 0; nt < 3; ++nt)
#pragma unroll
        for (int r = 0; r < 4; ++r)
            s_red[w][l][nt * 4 + r] = acc[nt][r];
    __syncthreads();

    if (t < GR * 47) {
        const int b_loc = t & 15;
        const int j     = t >> 4;
        const int lane  = ((b_loc >> 2) << 4) | (j & 15);
        const int reg   = ((j >> 4) << 2) | (b_loc & 3);
        float s = 0.f;
#pragma unroll
        for (int q = 0; q < NWV; ++q) s += s_red[q][lane][reg];
        s_c[b_loc][j] = s;
    }
    __syncthreads();

    if (t < GR * KK) {
        const int k     = t >> 4;
        const int b_loc = t & 15;
        const int b     = b0 + b_loc;

        float logits[KK];
#pragma unroll
        for (int kk = 0; kk < KK; ++kk) logits[kk] = s_c[b_loc][kk] + bmix[kk];

        float m[3];
#pragma unroll
        for (int c = 0; c < 3; ++c)
            m[c] = (k > 0) ? (s_c[b_loc][5 + (k - 1) * 3 + c] + bmean[(k - 1) * 3 + c]) : 0.f;

        float sc[6];
#pragma unroll
        for (int c = 0; c < 6; ++c)
            sc[c] = s_c[b_loc][17 + k * 6 + c] + bscale[k * 6 + c];

        float mx = logits[0];
#pragma unroll
        for (int kk = 1; kk < KK; ++kk) mx = fmaxf(mx, logits[kk]);
        float den = 0.f;
#pragma unroll
        for (int kk = 0; kk < KK; ++kk) den += expf(logits[kk] - mx);
        const float wgt = expf(logits[k] - mx) / den;

        const float L00 = softplus_f(sc[0]);
        const float L10 = sc[1];
        const float L11 = softplus_f(sc[2]);
        const float L20 = sc[3];
        const float L21 = sc[4];
        const float L22 = softplus_f(sc[5]);

        const float r00 = 1.f / L00;
        const float r11 = 1.f / L11;
        const float r22 = 1.f / L22;
        const float a   = wgt * r00 * r11 * r22 * INV_2PI_POW15;

        s_L[b_loc][k][0] = L00;
        s_L[b_loc][k][1] = L10;
        s_L[b_loc][k][2] = L11;
        s_L[b_loc][k][3] = L20;
        s_L[b_loc][k][4] = L21;
        s_L[b_loc][k][5] = L22;

        float pv[10] = { m[0], m[1], m[2], r00, L10, r11, L20, L21, r22, a };
#pragma unroll
        for (int i = 0; i < 10; ++i) {
            const int q = k * 10 + i;
            par4[(((size_t)(q >> 2)) * BB + b) * 4 + (q & 3)] = pv[i];
        }
    }
    __syncthreads();

    if (t < GR * KK * 9) {
        const int b_loc = t / 45;
        const int rem   = t - b_loc * 45;
        const int k     = rem / 9;
        const int e9    = rem - k * 9;
        const int rr    = e9 / 3;
        const int cc    = e9 - rr * 3;
        const float v = (cc > rr) ? 0.f : s_L[b_loc][k][(rr * (rr + 1)) / 2 + cc];
        Lout[(size_t)b0 * 45 + t] = v;
    }
}

// ---------------------------------------------------------------------------
// Kernel 2: eval with LDS-staged dxyz. Block = (btile of 256 b, ptile of 7 p).
// Stage: 1344 float4 = 21 perfectly-coalesced 1KB wave-loads (rows of 768
// floats = 3x64-lane spans, no row straddle). Read: stride-3 LDS (2-way
// bank alias = free). All loads cached (no NT).
// ---------------------------------------------------------------------------
__global__ __launch_bounds__(256) void eval_kernel(
    const float* __restrict__ dxyz,
    const float* __restrict__ par4,
    float* __restrict__ out)
{
    __shared__ float s_x[PTS][768];        // 21 KB

    const int t  = threadIdx.x;
    const int bt = blockIdx.x;             // 0..15
    const int pt = blockIdx.y;             // 0..188
    const int b  = bt * 256 + t;
    const int p0 = pt * PTS;

    // ---- per-thread params: 13 coalesced f32x4 (L2-resident) ----
    float pr[NG * 4];
#pragma unroll
    for (int g = 0; g < NG; ++g) {
        const f32x4 v = *(const f32x4*)(par4 + ((size_t)g * BB + b) * 4);
        pr[g * 4 + 0] = v[0];
        pr[g * 4 + 1] = v[1];
        pr[g * 4 + 2] = v[2];
        pr[g * 4 + 3] = v[3];
    }

    // ---- stage dxyz tile: 7 p-rows x 768 floats, fully coalesced float4 ----
#pragma unroll
    for (int e4 = t; e4 < PTS * 192; e4 += 256) {
        const int i  = e4 / 192;
        const int c4 = e4 - i * 192;
        const f32x4 v = *(const f32x4*)(dxyz + (((size_t)(p0 + i) * BB) + bt * 256) * 3 + c4 * 4);
        *(f32x4*)(&s_x[i][c4 * 4]) = v;
    }
    __syncthreads();

    // ---- compute 7 points ----
#pragma unroll
    for (int i = 0; i < PTS; ++i) {
        const float x0 = s_x[i][t * 3 + 0];
        const float x1 = s_x[i][t * 3 + 1];
        const float x2 = s_x[i][t * 3 + 2];

        float res = 0.f;
#pragma unroll
        for (int k = 0; k < KK; ++k) {
            const float d0 = x0 - pr[k * 10 + 0];
            const float d1 = x1 - pr[k * 10 + 1];
            const float d2 = x2 - pr[k * 10 + 2];
            const float z0 = d0 * pr[k * 10 + 3];
            const float z1 = fmaf(-pr[k * 10 + 4], z0, d1) * pr[k * 10 + 5];
            const float z2 = fmaf(-pr[k * 10 + 7], z1, fmaf(-pr[k * 10 + 6], z0, d2)) * pr[k * 10 + 8];
            const float q  = fmaf(z2, z2, fmaf(z1, z1, z0 * z0));
            res = fmaf(pr[k * 10 + 9], __expf(-0.5f * q), res);
        }
        out[(size_t)(p0 + i) * BB + b] = res;
    }
}

extern "C" void kernel_launch(void* const* d_in, const int* in_sizes, int n_in,
                              void* d_out, int out_size, void* d_ws, size_t ws_size,
                              hipStream_t stream) {
    const float* rep    = (const float*)d_in[0];
    const float* dxyz   = (const float*)d_in[1];
    const float* Wmix   = (const float*)d_in[2];
    const float* bmix   = (const float*)d_in[3];
    const float* Wmean  = (const float*)d_in[4];
    const float* bmean  = (const float*)d_in[5];
    const float* Wscale = (const float*)d_in[6];
    const float* bscale = (const float*)d_in[7];

    float* out  = (float*)d_out;
    float* Lout = out + (size_t)BB * PP;          // second tuple output

    float* par4 = (float*)d_ws;                   // NG*BB*4 f32 (852 KB)
    short* Wpk  = (short*)(par4 + (size_t)NG * BB * 4);  // 49152 bf16 (98 KB)

    pack_kernel<<<192, 256, 0, stream>>>(Wmix, Wmean, Wscale, Wpk);

    head_fused_kernel<<<BB / GR, 1024, 0, stream>>>(rep, Wpk, bmix, bmean, bscale, Lout, par4);

    eval_kernel<<<dim3(BB / 256, NPT), 256, 0, stream>>>(dxyz, par4, out);
}